// Round 5
// baseline (48.516 us; speedup 1.0000x reference)
//
#include <hip/hip_runtime.h>

#define BLOCK 256
#define GRID  512            // 2 blocks/CU (LDS-limited: 60.8 KB/block)
#define NB 5000
#define NP 2000
#define TILE 256             // float4-groups per tile (1 group = 4 pairs per thread)

// async global->LDS, 16B per lane; LDS dest is wave-uniform base (+lane*16 in HW)
__device__ __forceinline__ void glds16(const void* g, void* l) {
    __builtin_amdgcn_global_load_lds(
        (const __attribute__((address_space(1))) unsigned int*)g,
        (__attribute__((address_space(3))) unsigned int*)l,
        16, 0, 0);
}

__global__ __launch_bounds__(BLOCK) void vs_ll_kernel(
    const float* __restrict__ v1, const float* __restrict__ v2,
    const float* __restrict__ weight,
    const float* __restrict__ e1, const float* __restrict__ e2,
    const int*  __restrict__ bidx, const int* __restrict__ pidx,
    int nb, int np, int n,
    float* __restrict__ partials, unsigned int* __restrict__ counter,
    float* __restrict__ out)
{
    __shared__ float s_v1[NB];
    __shared__ float s_v2[NP];
    __shared__ float s_e1[2][TILE * 4];
    __shared__ float s_e2[2][TILE * 4];
    __shared__ int   s_bi[2][TILE * 4];
    __shared__ int   s_pi[2][TILE * 4];
    __shared__ float s_red[BLOCK / 64];
    __shared__ unsigned int s_last;

    const int tid  = threadIdx.x;
    const int wid  = tid >> 6;

    // stage gather tables into LDS, vectorized
    {
        const float4* v1v = (const float4*)v1;
        const float4* v2v = (const float4*)v2;
        float4* s1v = (float4*)s_v1;
        float4* s2v = (float4*)s_v2;
        const int nb4 = nb >> 2, np4 = np >> 2;
        for (int i = tid; i < nb4; i += BLOCK) s1v[i] = v1v[i];
        for (int i = tid; i < np4; i += BLOCK) s2v[i] = v2v[i];
        for (int i = (nb4 << 2) + tid; i < nb; i += BLOCK) s_v1[i] = v1[i];
        for (int i = (np4 << 2) + tid; i < np; i += BLOCK) s_v2[i] = v2[i];
    }

    const float w     = weight[0];
    const float onemw = 1.0f - w;
    const float LOG_LO = -13.815511f;      // log(1e-6)
    const float LOG_HI = -1.0000005e-6f;   // log(0.999999)

    const int n4 = n >> 2;                 // 2.5M float4-groups (n divisible by 4)
    const int NT = (n4 + TILE - 1) / TILE; // total tiles

    // per-wave LDS dest base for this wave's 1KB chunk of each buffer
    const int woff = wid * 64 * 4;         // element offset (64 lanes * 4 elems)

    // issue the 4 async stream loads for tile tl into buffer c (4 glds/wave)
    auto issue_tile = [&](int tl, int c) {
        int g  = tl * TILE + tid;
        int gc = g < n4 ? g : n4 - 1;      // clamp OOB lanes (masked in compute)
        glds16(e1 + (size_t)gc * 4,   &s_e1[c][woff]);
        glds16(e2 + (size_t)gc * 4,   &s_e2[c][woff]);
        glds16(bidx + (size_t)gc * 4, &s_bi[c][woff]);
        glds16(pidx + (size_t)gc * 4, &s_pi[c][woff]);
    };

    float acc = 0.0f;
    int tl = blockIdx.x;
    if (tl < NT) issue_tile(tl, 0);
    __syncthreads();   // tables visible; one-time full drain (tile0 landed too)

    int cur = 0;
    for (; tl < NT; tl += GRID, cur ^= 1) {
        const int  tnext    = tl + GRID;
        const bool has_next = tnext < NT;
        if (has_next) {
            issue_tile(tnext, cur ^ 1);
            asm volatile("s_waitcnt vmcnt(4)" ::: "memory"); // tile tl's 4 glds done
        } else {
            asm volatile("s_waitcnt vmcnt(0)" ::: "memory");
        }
        __builtin_amdgcn_s_barrier();      // all waves' tile-tl data visible

        // compute this thread's group (4 pairs) from LDS
        {
            const int g = tl * TILE + tid;
            float4 A = ((const float4*)s_e1[cur])[tid];
            float4 C = ((const float4*)s_e2[cur])[tid];
            int4   B = ((const int4*)s_bi[cur])[tid];
            int4   P = ((const int4*)s_pi[cur])[tid];

            float bb[4] = { s_v1[B.x], s_v1[B.y], s_v1[B.z], s_v1[B.w] };
            float pp[4] = { s_v2[P.x], s_v2[P.y], s_v2[P.z], s_v2[P.w] };
            float u1[4] = { A.x, A.y, A.z, A.w };
            float u2[4] = { C.x, C.y, C.z, C.w };

            float gacc = 0.0f;
            #pragma unroll
            for (int j = 0; j < 4; ++j) {
                float z  = fmaf(w, bb[j], onemw * pp[j]);
                float az = fabsf(z);
                // l = log1p(exp(-|z|)); fast math fine vs 1.6e5 abs threshold
                float l  = __logf(1.0f + __expf(-az));
                float logp = -(fmaxf(-z, 0.0f) + l);   // log(sigmoid(z))
                float logq = -(fmaxf( z, 0.0f) + l);   // log(1-sigmoid(z))
                logp = fminf(fmaxf(logp, LOG_LO), LOG_HI);
                logq = fminf(fmaxf(logq, LOG_LO), LOG_HI);
                gacc = fmaf(u1[j], logp, gacc);
                gacc = fmaf(u2[j], logq, gacc);
            }
            acc += (g < n4) ? gacc : 0.0f;
        }

        __builtin_amdgcn_s_barrier();      // protect buf[cur] before overwrite issue
    }

    // wave reduce (64 lanes)
    #pragma unroll
    for (int off = 32; off > 0; off >>= 1)
        acc += __shfl_down(acc, off, 64);

    const int lane = tid & 63;
    if (lane == 0) s_red[wid] = acc;
    __syncthreads();
    if (tid == 0) {
        float t = 0.0f;
        #pragma unroll
        for (int k = 0; k < BLOCK / 64; ++k) t += s_red[k];
        partials[blockIdx.x] = t;
        __threadfence();                        // publish partial (device scope)
        unsigned int ticket = atomicAdd(counter, 1u);
        s_last = (ticket == GRID - 1) ? 1u : 0u;
    }
    __syncthreads();

    // last block (by ticket) performs the deterministic final reduction:
    // fixed 512->256 add + fixed shfl tree, independent of which block runs it
    if (s_last) {
        __threadfence();
        const volatile float* vp = (const volatile float*)partials;
        float v = vp[tid] + vp[tid + 256];
        #pragma unroll
        for (int off = 32; off > 0; off >>= 1)
            v += __shfl_down(v, off, 64);
        if (lane == 0) s_red[wid] = v;
        __syncthreads();
        if (tid == 0) {
            float t = 0.0f;
            #pragma unroll
            for (int k = 0; k < BLOCK / 64; ++k) t += s_red[k];
            out[0] = t;
        }
    }
}

extern "C" void kernel_launch(void* const* d_in, const int* in_sizes, int n_in,
                              void* d_out, int out_size, void* d_ws, size_t ws_size,
                              hipStream_t stream) {
    const float* v1     = (const float*)d_in[0];
    const float* v2     = (const float*)d_in[1];
    const float* weight = (const float*)d_in[2];
    const float* e1     = (const float*)d_in[3];
    const float* e2     = (const float*)d_in[4];
    const int*   bidx   = (const int*)d_in[5];
    const int*   pidx   = (const int*)d_in[6];

    const int nb = in_sizes[0];
    const int np = in_sizes[1];
    const int n  = in_sizes[3];

    float*        partials = (float*)d_ws;
    unsigned int* counter  = (unsigned int*)((char*)d_ws + 4096);
    float*        out      = (float*)d_out;

    // zero the ticket counter (harness poisons d_ws to 0xAA, and replays
    // must each start from 0) — async memset is graph-capture safe
    hipMemsetAsync(counter, 0, sizeof(unsigned int), stream);

    vs_ll_kernel<<<GRID, BLOCK, 0, stream>>>(v1, v2, weight, e1, e2, bidx, pidx,
                                             nb, np, n, partials, counter, out);
}

// Round 6
// 33.278 us; speedup vs baseline: 1.4579x; 1.4579x over previous
//
#include <hip/hip_runtime.h>

#define BLOCK 256
#define GRID  512            // 2 blocks/CU (LDS-limited: 76.9 KB/block)
#define NB 5000
#define NP 2000
#define TILE 256             // float4-groups per tile; 16 KB LDS per tile (4 arrays)
#define DEPTH 3              // pipeline depth (ring of 3 tile buffers)

// async global->LDS, 16B per lane; LDS dest is wave-uniform base (+lane*16 in HW)
__device__ __forceinline__ void glds16(const void* g, void* l) {
    __builtin_amdgcn_global_load_lds(
        (const __attribute__((address_space(1))) unsigned int*)g,
        (__attribute__((address_space(3))) unsigned int*)l,
        16, 0, 0);
}

__global__ __launch_bounds__(BLOCK) void vs_ll_kernel(
    const float* __restrict__ v1, const float* __restrict__ v2,
    const float* __restrict__ weight,
    const float* __restrict__ e1, const float* __restrict__ e2,
    const int*  __restrict__ bidx, const int* __restrict__ pidx,
    int nb, int np, int n, float* __restrict__ partials)
{
    __shared__ float s_v1[NB];
    __shared__ float s_v2[NP];
    __shared__ float s_e1[DEPTH][TILE * 4];
    __shared__ float s_e2[DEPTH][TILE * 4];
    __shared__ int   s_bi[DEPTH][TILE * 4];
    __shared__ int   s_pi[DEPTH][TILE * 4];
    __shared__ float s_red[BLOCK / 64];

    const int tid = threadIdx.x;
    const int wid = tid >> 6;

    // stage gather tables into LDS, vectorized
    {
        const float4* v1v = (const float4*)v1;
        const float4* v2v = (const float4*)v2;
        float4* s1v = (float4*)s_v1;
        float4* s2v = (float4*)s_v2;
        const int nb4 = nb >> 2, np4 = np >> 2;
        for (int i = tid; i < nb4; i += BLOCK) s1v[i] = v1v[i];
        for (int i = tid; i < np4; i += BLOCK) s2v[i] = v2v[i];
        for (int i = (nb4 << 2) + tid; i < nb; i += BLOCK) s_v1[i] = v1[i];
        for (int i = (np4 << 2) + tid; i < np; i += BLOCK) s_v2[i] = v2[i];
    }
    __syncthreads();                       // tables visible (drains staging loads)

    const float w     = weight[0];
    const float onemw = 1.0f - w;
    const float LOG_LO = -13.815511f;      // log(1e-6)
    const float LOG_HI = -1.0000005e-6f;   // log(0.999999)

    const int n4 = n >> 2;                 // float4-groups (n divisible by 4)
    const int NT = (n4 + TILE - 1) / TILE; // total tiles

    // tiles owned by this block: tl = bid + m*GRID, m = 0..M-1
    const int bid = blockIdx.x;
    const int M   = (bid < NT) ? (NT - bid + GRID - 1) / GRID : 0;

    // per-wave LDS dest base (64 lanes * 4 elems per lane)
    const int woff = wid * 64 * 4;

    auto issue_tile = [&](int m, int c) {
        int g  = (bid + m * GRID) * TILE + tid;
        int gc = g < n4 ? g : n4 - 1;      // clamp OOB lanes (masked in compute)
        glds16(e1 + (size_t)gc * 4,   &s_e1[c][woff]);
        glds16(e2 + (size_t)gc * 4,   &s_e2[c][woff]);
        glds16(bidx + (size_t)gc * 4, &s_bi[c][woff]);
        glds16(pidx + (size_t)gc * 4, &s_pi[c][woff]);
    };

    // prologue: 2 tiles in flight before the loop
    if (M > 0) issue_tile(0, 0);
    if (M > 1) issue_tile(1, 1);

    float acc = 0.0f;
    int cur = 0, c2 = 2;                   // cur = m%3, c2 = (m+2)%3
    for (int m = 0; m < M; ++m) {
        if (m + 2 < M) {
            issue_tile(m + 2, c2);
            asm volatile("s_waitcnt vmcnt(8)" ::: "memory");  // tile m done
        } else if (m + 1 < M) {
            asm volatile("s_waitcnt vmcnt(4)" ::: "memory");
        } else {
            asm volatile("s_waitcnt vmcnt(0)" ::: "memory");
        }
        __builtin_amdgcn_s_barrier();      // all waves' tile-m data visible

        {
            const int g = (bid + m * GRID) * TILE + tid;
            float4 A = ((const float4*)s_e1[cur])[tid];
            float4 C = ((const float4*)s_e2[cur])[tid];
            int4   B = ((const int4*)s_bi[cur])[tid];
            int4   P = ((const int4*)s_pi[cur])[tid];

            float bb[4] = { s_v1[B.x], s_v1[B.y], s_v1[B.z], s_v1[B.w] };
            float pp[4] = { s_v2[P.x], s_v2[P.y], s_v2[P.z], s_v2[P.w] };
            float u1[4] = { A.x, A.y, A.z, A.w };
            float u2[4] = { C.x, C.y, C.z, C.w };

            float gacc = 0.0f;
            #pragma unroll
            for (int j = 0; j < 4; ++j) {
                float z  = fmaf(w, bb[j], onemw * pp[j]);
                float az = fabsf(z);
                // l = log1p(exp(-|z|)); fast math fine vs 1.6e5 abs threshold
                float l  = __logf(1.0f + __expf(-az));
                float logp = -(fmaxf(-z, 0.0f) + l);   // log(sigmoid(z))
                float logq = -(fmaxf( z, 0.0f) + l);   // log(1-sigmoid(z))
                logp = fminf(fmaxf(logp, LOG_LO), LOG_HI);
                logq = fminf(fmaxf(logq, LOG_LO), LOG_HI);
                gacc = fmaf(u1[j], logp, gacc);
                gacc = fmaf(u2[j], logq, gacc);
            }
            acc += (g < n4) ? gacc : 0.0f;
        }

        __builtin_amdgcn_s_barrier();      // protect buf[cur] before reuse by issue

        cur = (cur == 2) ? 0 : cur + 1;
        c2  = (c2  == 2) ? 0 : c2  + 1;
    }

    // wave reduce (64 lanes)
    #pragma unroll
    for (int off = 32; off > 0; off >>= 1)
        acc += __shfl_down(acc, off, 64);

    const int lane = tid & 63;
    if (lane == 0) s_red[wid] = acc;
    __syncthreads();
    if (tid == 0) {
        float t = 0.0f;
        #pragma unroll
        for (int k = 0; k < BLOCK / 64; ++k) t += s_red[k];
        partials[bid] = t;
    }
}

// minimal 1-wave tail: deterministic fixed-order reduction of GRID partials
__global__ __launch_bounds__(64) void vs_reduce_kernel(
    const float* __restrict__ partials, float* __restrict__ out)
{
    const int tid = threadIdx.x;
    float acc = 0.0f;
    #pragma unroll
    for (int k = 0; k < GRID / 64; ++k) acc += partials[tid + k * 64];
    #pragma unroll
    for (int off = 32; off > 0; off >>= 1)
        acc += __shfl_down(acc, off, 64);
    if (tid == 0) out[0] = acc;
}

extern "C" void kernel_launch(void* const* d_in, const int* in_sizes, int n_in,
                              void* d_out, int out_size, void* d_ws, size_t ws_size,
                              hipStream_t stream) {
    const float* v1     = (const float*)d_in[0];
    const float* v2     = (const float*)d_in[1];
    const float* weight = (const float*)d_in[2];
    const float* e1     = (const float*)d_in[3];
    const float* e2     = (const float*)d_in[4];
    const int*   bidx   = (const int*)d_in[5];
    const int*   pidx   = (const int*)d_in[6];

    const int nb = in_sizes[0];
    const int np = in_sizes[1];
    const int n  = in_sizes[3];

    float* partials = (float*)d_ws;
    float* out      = (float*)d_out;

    vs_ll_kernel<<<GRID, BLOCK, 0, stream>>>(v1, v2, weight, e1, e2, bidx, pidx,
                                             nb, np, n, partials);
    vs_reduce_kernel<<<1, 64, 0, stream>>>(partials, out);
}